// Round 1
// baseline (1131.624 us; speedup 1.0000x reference)
//
#include <hip/hip_runtime.h>

// LoHA: out = x @ (W + (a0@b0/16) * (a1@b1/16)) + bias
// x: [16384, 4096] fp32, W: [4096,4096] fp32, out: [16384,4096] fp32.
// Strategy: build fused kernel matrix transposed in bf16 (Bt[n][k]),
// cast x to bf16, then m97-style MFMA GEMM (128x128 tile, BK=32,
// global_load_lds width-16 staging, ds_read_b128 fragments).
// Workspace: xb (bf16, 134217728 B) @ 0; Bt (bf16, 33554432 B) @ 134217728.

#define D_IN   4096
#define D_OUT  4096
#define RANKR  16
#define MROWS  16384

typedef __attribute__((ext_vector_type(8))) short short8;
typedef __attribute__((ext_vector_type(4))) float floatx4;

__device__ __forceinline__ unsigned short f2bf(float f) {
    union { float f; unsigned u; } c; c.f = f;
    unsigned r = c.u + 0x7fffu + ((c.u >> 16) & 1u);   // round-to-nearest-even
    return (unsigned short)(r >> 16);
}

__device__ __forceinline__ void glds16(const void* g, void* l) {
    __builtin_amdgcn_global_load_lds(
        (const __attribute__((address_space(1))) void*)g,
        (__attribute__((address_space(3))) void*)l, 16, 0, 0);
}

// ---------------------------------------------------------------------------
// Kernel 1: Bt[n][k] = bf16( W[k][n] + (s * a0[k,:]@b0[:,n]) * (s * a1[k,:]@b1[:,n]) )
// 64x64 tiles; W-read coalesced in n, Bt-write coalesced in k via LDS transpose.
// ---------------------------------------------------------------------------
__global__ __launch_bounds__(256) void build_bt(
    const float* __restrict__ W,  const float* __restrict__ a0,
    const float* __restrict__ b0, const float* __restrict__ a1,
    const float* __restrict__ b1, unsigned short* __restrict__ Bt) {
    __shared__ float Wt[64][65];                 // +1 pad: phase-2 column reads conflict-free
    __shared__ float a0t[64][17], a1t[64][17];   // +1 pad
    __shared__ float b0t[16][64], b1t[16][64];   // wave-uniform reads (broadcast)
    const int tid = threadIdx.x;
    const int k0 = blockIdx.x * 64, n0 = blockIdx.y * 64;

    #pragma unroll
    for (int i = 0; i < 16; ++i) {
        int e = i * 256 + tid;
        int kk = e >> 6, nn = e & 63;
        Wt[kk][nn] = W[(size_t)(k0 + kk) * D_OUT + n0 + nn];
    }
    #pragma unroll
    for (int i = 0; i < 4; ++i) {
        int e = i * 256 + tid;
        int kk = e >> 4, r = e & 15;
        a0t[kk][r] = a0[(k0 + kk) * RANKR + r];
        a1t[kk][r] = a1[(k0 + kk) * RANKR + r];
    }
    #pragma unroll
    for (int i = 0; i < 4; ++i) {
        int e = i * 256 + tid;
        int r = e >> 6, nn = e & 63;
        b0t[r][nn] = b0[(size_t)r * D_OUT + n0 + nn];
        b1t[r][nn] = b1[(size_t)r * D_OUT + n0 + nn];
    }
    __syncthreads();

    const float s = 1.0f / 16.0f;  // ALPHA / RANK
    #pragma unroll 4
    for (int i = 0; i < 16; ++i) {
        int e = i * 256 + tid;
        int kk = e & 63, nn = e >> 6;   // kk == lane -> contiguous bf16 stores
        float d0 = 0.f, d1 = 0.f;
        #pragma unroll
        for (int r = 0; r < RANKR; ++r) {
            d0 += a0t[kk][r] * b0t[r][nn];
            d1 += a1t[kk][r] * b1t[r][nn];
        }
        float v = Wt[kk][nn] + (s * d0) * (s * d1);
        Bt[(size_t)(n0 + nn) * D_IN + k0 + kk] = f2bf(v);
    }
}

// ---------------------------------------------------------------------------
// Kernel 2: x fp32 -> bf16, 8 elements/thread, 16B stores.
// ---------------------------------------------------------------------------
__global__ __launch_bounds__(256) void cvt_x(
    const float* __restrict__ x, unsigned short* __restrict__ xb) {
    size_t i = ((size_t)blockIdx.x * 256 + threadIdx.x) * 8;
    const float4* p = (const float4*)(x + i);
    float4 v0 = p[0], v1 = p[1];
    union { unsigned short u[8]; uint4 q; } o;
    o.u[0] = f2bf(v0.x); o.u[1] = f2bf(v0.y);
    o.u[2] = f2bf(v0.z); o.u[3] = f2bf(v0.w);
    o.u[4] = f2bf(v1.x); o.u[5] = f2bf(v1.y);
    o.u[6] = f2bf(v1.z); o.u[7] = f2bf(v1.w);
    *(uint4*)(xb + i) = o.q;
}

// ---------------------------------------------------------------------------
// Kernel 3: C[m][n] = sum_k A[m][k]*Bt[n][k] + bias[n]   (bf16 MFMA, fp32 acc)
// 128x128 block tile, BK=32, 4 waves in 2x2, each wave 64x64 = 4x4 MFMA tiles.
// ---------------------------------------------------------------------------
__global__ __launch_bounds__(256) void gemm_bt(
    const unsigned short* __restrict__ A,   // [MROWS][D_IN] bf16
    const unsigned short* __restrict__ B,   // [D_OUT][D_IN] bf16 (transposed kernel)
    const float* __restrict__ bias,
    float* __restrict__ C) {
    __shared__ __align__(16) unsigned short As[128 * 32];
    __shared__ __align__(16) unsigned short Bs[128 * 32];

    const int tid  = threadIdx.x;
    const int wave = tid >> 6, lane = tid & 63;
    const int quad = lane >> 4, l16 = lane & 15;
    const int m0 = blockIdx.y * 128, n0 = blockIdx.x * 128;
    const int wm = (wave >> 1) * 64, wn = (wave & 1) * 64;

    const unsigned short* Ag = A + (size_t)m0 * D_IN;
    const unsigned short* Bg = B + (size_t)n0 * D_IN;

    floatx4 acc[4][4] = {};

    for (int kt = 0; kt < D_IN; kt += 32) {
        // stage A-tile [128][32] and B-tile [128][32] via async global->LDS, 16B/lane
        #pragma unroll
        for (int p = 0; p < 2; ++p) {
            int t   = p * 256 + tid;             // 0..511, lane-contiguous
            int row = t >> 2;
            int cc  = (t & 3) * 8;
            unsigned ldsoff = (unsigned)(p * 4096 + wave * 1024);  // wave-uniform base (bytes)
            glds16(Ag + (size_t)row * D_IN + kt + cc, (char*)As + ldsoff);
            glds16(Bg + (size_t)row * D_IN + kt + cc, (char*)Bs + ldsoff);
        }
        __syncthreads();   // compiler drains vmcnt before s_barrier

        short8 af[4], bf[4];
        #pragma unroll
        for (int mt = 0; mt < 4; ++mt)
            af[mt] = *(const short8*)(As + (wm + mt * 16 + l16) * 32 + quad * 8);
        #pragma unroll
        for (int nt = 0; nt < 4; ++nt)
            bf[nt] = *(const short8*)(Bs + (wn + nt * 16 + l16) * 32 + quad * 8);
        #pragma unroll
        for (int mt = 0; mt < 4; ++mt)
            #pragma unroll
            for (int nt = 0; nt < 4; ++nt)
                acc[mt][nt] = __builtin_amdgcn_mfma_f32_16x16x32_bf16(
                    af[mt], bf[nt], acc[mt][nt], 0, 0, 0);
        __syncthreads();
    }

    // epilogue: C/D layout col=lane&15, row=quad*4+reg; fuse bias
    #pragma unroll
    for (int nt = 0; nt < 4; ++nt) {
        int col = n0 + wn + nt * 16 + l16;
        float bv = bias[col];
        #pragma unroll
        for (int mt = 0; mt < 4; ++mt) {
            int r0 = m0 + wm + mt * 16 + quad * 4;
            #pragma unroll
            for (int r = 0; r < 4; ++r)
                C[(size_t)(r0 + r) * D_OUT + col] = acc[mt][nt][r] + bv;
        }
    }
}

extern "C" void kernel_launch(void* const* d_in, const int* in_sizes, int n_in,
                              void* d_out, int out_size, void* d_ws, size_t ws_size,
                              hipStream_t stream) {
    const float* x    = (const float*)d_in[0];
    const float* W    = (const float*)d_in[1];
    const float* bias = (const float*)d_in[2];
    const float* a0   = (const float*)d_in[3];
    const float* b0   = (const float*)d_in[4];
    const float* a1   = (const float*)d_in[5];
    const float* b1   = (const float*)d_in[6];
    float* out = (float*)d_out;

    unsigned short* xb = (unsigned short*)d_ws;                       // 128 MB
    unsigned short* Bt = (unsigned short*)((char*)d_ws + (size_t)MROWS * D_IN * 2);  // 32 MB

    build_bt<<<dim3(D_IN / 64, D_OUT / 64), 256, 0, stream>>>(W, a0, b0, a1, b1, Bt);
    cvt_x<<<(MROWS * (size_t)D_IN) / (8 * 256), 256, 0, stream>>>(x, xb);
    gemm_bt<<<dim3(D_OUT / 128, MROWS / 128), 256, 0, stream>>>(xb, Bt, bias, out);
}

// Round 2
// 1094.031 us; speedup vs baseline: 1.0344x; 1.0344x over previous
//
#include <hip/hip_runtime.h>

// LoHA: out = x @ (W + (a0@b0/16) * (a1@b1/16)) + bias
// x: [16384, 4096] fp32, W: [4096,4096] fp32, out: [16384,4096] fp32.
// R2: (1) XOR-swizzled LDS staging (chunk ^= (row>>2)&3, applied on the GLOBAL
//     address per lane so global_load_lds's lane-contiguous LDS write is kept,
//     coalescing unchanged) -> kills the 8-way ds_read_b128 bank conflicts
//     (6.7e7 conflict cycles = +4 cyc/read in R1).
//     (2) non-temporal C stores (don't evict B-tiles from L2/L3).
//     (3) build_bt + cvt_x fused into one launch (prep) to cut serialization.
// Workspace: xb (bf16, 134217728 B) @ 0; Bt (bf16, 33554432 B) @ 134217728.

#define D_IN   4096
#define D_OUT  4096
#define RANKR  16
#define MROWS  16384

typedef __attribute__((ext_vector_type(8))) short short8;
typedef __attribute__((ext_vector_type(4))) float floatx4;

__device__ __forceinline__ unsigned short f2bf(float f) {
    union { float f; unsigned u; } c; c.f = f;
    unsigned r = c.u + 0x7fffu + ((c.u >> 16) & 1u);   // round-to-nearest-even
    return (unsigned short)(r >> 16);
}

__device__ __forceinline__ void glds16(const void* g, void* l) {
    __builtin_amdgcn_global_load_lds(
        (const __attribute__((address_space(1))) void*)g,
        (__attribute__((address_space(3))) void*)l, 16, 0, 0);
}

// ---------------------------------------------------------------------------
// prep: blocks [0,4096) build Bt[n][k] = bf16(W[k][n] + (s*a0b0)*(s*a1b1));
//       blocks [4096,36864) convert x fp32 -> bf16 (8 elem/thread, 16B stores)
// ---------------------------------------------------------------------------
__global__ __launch_bounds__(256) void prep(
    const float* __restrict__ W,  const float* __restrict__ a0,
    const float* __restrict__ b0, const float* __restrict__ a1,
    const float* __restrict__ b1, unsigned short* __restrict__ Bt,
    const float* __restrict__ x,  unsigned short* __restrict__ xb) {
    const int tid = threadIdx.x;
    if (blockIdx.x >= 4096) {
        size_t i = ((size_t)(blockIdx.x - 4096) * 256 + tid) * 8;
        const float4* p = (const float4*)(x + i);
        float4 v0 = p[0], v1 = p[1];
        union { unsigned short u[8]; uint4 q; } o;
        o.u[0] = f2bf(v0.x); o.u[1] = f2bf(v0.y);
        o.u[2] = f2bf(v0.z); o.u[3] = f2bf(v0.w);
        o.u[4] = f2bf(v1.x); o.u[5] = f2bf(v1.y);
        o.u[6] = f2bf(v1.z); o.u[7] = f2bf(v1.w);
        *(uint4*)(xb + i) = o.q;
        return;
    }
    __shared__ float Wt[64][65];
    __shared__ float a0t[64][17], a1t[64][17];
    __shared__ float b0t[16][64], b1t[16][64];
    const int k0 = (blockIdx.x & 63) * 64, n0 = (blockIdx.x >> 6) * 64;

    #pragma unroll
    for (int i = 0; i < 16; ++i) {
        int e = i * 256 + tid;
        int kk = e >> 6, nn = e & 63;
        Wt[kk][nn] = W[(size_t)(k0 + kk) * D_OUT + n0 + nn];
    }
    #pragma unroll
    for (int i = 0; i < 4; ++i) {
        int e = i * 256 + tid;
        int kk = e >> 4, r = e & 15;
        a0t[kk][r] = a0[(k0 + kk) * RANKR + r];
        a1t[kk][r] = a1[(k0 + kk) * RANKR + r];
    }
    #pragma unroll
    for (int i = 0; i < 4; ++i) {
        int e = i * 256 + tid;
        int r = e >> 6, nn = e & 63;
        b0t[r][nn] = b0[(size_t)r * D_OUT + n0 + nn];
        b1t[r][nn] = b1[(size_t)r * D_OUT + n0 + nn];
    }
    __syncthreads();

    const float s = 1.0f / 16.0f;  // ALPHA / RANK
    #pragma unroll 4
    for (int i = 0; i < 16; ++i) {
        int e = i * 256 + tid;
        int kk = e & 63, nn = e >> 6;   // kk == lane -> contiguous bf16 stores
        float d0 = 0.f, d1 = 0.f;
        #pragma unroll
        for (int r = 0; r < RANKR; ++r) {
            d0 += a0t[kk][r] * b0t[r][nn];
            d1 += a1t[kk][r] * b1t[r][nn];
        }
        float v = Wt[kk][nn] + (s * d0) * (s * d1);
        Bt[(size_t)(n0 + nn) * D_IN + k0 + kk] = f2bf(v);
    }
}

// ---------------------------------------------------------------------------
// gemm: C[m][n] = sum_k A[m][k]*Bt[n][k] + bias[n]   (bf16 MFMA, fp32 acc)
// 128x128 block tile, BK=32, 4 waves 2x2, each wave 64x64 = 4x4 16x16x32 MFMA.
// LDS tiles XOR-swizzled: position chunk p' holds global chunk p'^((row>>2)&3).
// ---------------------------------------------------------------------------
__global__ __launch_bounds__(256) void gemm_bt(
    const unsigned short* __restrict__ A,   // [MROWS][D_IN] bf16
    const unsigned short* __restrict__ B,   // [D_OUT][D_IN] bf16 (transposed)
    const float* __restrict__ bias,
    float* __restrict__ C) {
    __shared__ __align__(16) unsigned short As[128 * 32];
    __shared__ __align__(16) unsigned short Bs[128 * 32];

    const int tid  = threadIdx.x;
    const int wave = tid >> 6, lane = tid & 63;
    const int quad = lane >> 4, l16 = lane & 15;
    const int m0 = blockIdx.y * 128, n0 = blockIdx.x * 128;
    const int wm = (wave >> 1) * 64, wn = (wave & 1) * 64;
    const int swz = l16 >> 2;              // swizzle key for fragment reads

    const unsigned short* Ag = A + (size_t)m0 * D_IN;
    const unsigned short* Bg = B + (size_t)n0 * D_IN;

    floatx4 acc[4][4] = {};

    for (int kt = 0; kt < D_IN; kt += 32) {
        // stage [128][32] tiles; lane-contiguous LDS writes, global chunk
        // permuted within each row's 4 lanes: c = (t&3) ^ ((row>>2)&3)
        #pragma unroll
        for (int p = 0; p < 2; ++p) {
            int t   = p * 256 + tid;
            int row = t >> 2;
            int cc  = ((t & 3) ^ ((row >> 2) & 3)) * 8;
            unsigned ldsoff = (unsigned)(p * 4096 + wave * 1024);  // wave-uniform
            glds16(Ag + (size_t)row * D_IN + kt + cc, (char*)As + ldsoff);
            glds16(Bg + (size_t)row * D_IN + kt + cc, (char*)Bs + ldsoff);
        }
        __syncthreads();

        short8 af[4], bf[4];
        #pragma unroll
        for (int mt = 0; mt < 4; ++mt)
            af[mt] = *(const short8*)(As + (wm + mt * 16 + l16) * 32 + (quad ^ swz) * 8);
        #pragma unroll
        for (int nt = 0; nt < 4; ++nt)
            bf[nt] = *(const short8*)(Bs + (wn + nt * 16 + l16) * 32 + (quad ^ swz) * 8);
        #pragma unroll
        for (int mt = 0; mt < 4; ++mt)
            #pragma unroll
            for (int nt = 0; nt < 4; ++nt)
                acc[mt][nt] = __builtin_amdgcn_mfma_f32_16x16x32_bf16(
                    af[mt], bf[nt], acc[mt][nt], 0, 0, 0);
        __syncthreads();
    }

    // epilogue: C/D layout col=lane&15, row=quad*4+reg; fuse bias; NT stores
    #pragma unroll
    for (int nt = 0; nt < 4; ++nt) {
        int col = n0 + wn + nt * 16 + l16;
        float bv = bias[col];
        #pragma unroll
        for (int mt = 0; mt < 4; ++mt) {
            int r0 = m0 + wm + mt * 16 + quad * 4;
            #pragma unroll
            for (int r = 0; r < 4; ++r) {
                float v = acc[mt][nt][r] + bv;
                __builtin_nontemporal_store(v, &C[(size_t)(r0 + r) * D_OUT + col]);
            }
        }
    }
}

extern "C" void kernel_launch(void* const* d_in, const int* in_sizes, int n_in,
                              void* d_out, int out_size, void* d_ws, size_t ws_size,
                              hipStream_t stream) {
    const float* x    = (const float*)d_in[0];
    const float* W    = (const float*)d_in[1];
    const float* bias = (const float*)d_in[2];
    const float* a0   = (const float*)d_in[3];
    const float* b0   = (const float*)d_in[4];
    const float* a1   = (const float*)d_in[5];
    const float* b1   = (const float*)d_in[6];
    float* out = (float*)d_out;

    unsigned short* xb = (unsigned short*)d_ws;                                      // 128 MB
    unsigned short* Bt = (unsigned short*)((char*)d_ws + (size_t)MROWS * D_IN * 2);  // 32 MB

    prep<<<4096 + (MROWS * (size_t)D_IN) / 2048, 256, 0, stream>>>(
        W, a0, b0, a1, b1, Bt, x, xb);
    gemm_bt<<<dim3(D_OUT / 128, MROWS / 128), 256, 0, stream>>>(xb, Bt, bias, out);
}